// Round 4
// baseline (248.193 us; speedup 1.0000x reference)
//
#include <hip/hip_runtime.h>
#include <stdint.h>

// B=4, C=O=320, H=W=64 -> HW=4096, N2=32768 (dconv n<16384, h n>=16384),
// K=2880 (M pad 384 in Wr only), Kf=640.
// K-permutation: kk = g*72 + k*8 + cl, c = g*8+cl (g<40, k<9, cl<8); kkb=kk>>3=g*9+k.
// Sd packed-8 (dconv only): elem(kk,n) at ushort idx (kkb*16384+n)*8 + (kk&7).
// Xp (padded x, h half): [g][b][py 66][px 66][cl 8] bf16; interior = x, halo = 0.
// Cc packed-8: elem(o,n2) at (o>>3)*32768*8 + n2*8 + (o&7).
// Wr K-major packed-8: elem(o,kk) at (kkb*384 + o)*8 + (kk&7). W2 likewise (Kf).
//
// k_gemm (round 4): r2 skeleton (BM=160 x BN=128, 4 waves 2Mx2N, per-wave
// 80x64, dbuf B, one vmcnt(0)+barrier per K-step, grid 512 = 2 blk/CU) with:
//  - A-fragments loaded DIRECTLY global->VGPR from Wr (2.2 MB, L2-hot; L1
//    absorbs the wn-redundancy: 20 KB unique A-frags/block-step < 32 KB L1).
//    Removes 10/18 LDS reads per wave-step, 5/9 staging issues, and the A
//    entries from the end-of-step drain. LDS = Bs dbuf only (32 KB).
//  - Bijective XCD swizzle (512 blocks, 64-chunk per XCD; same-m0 blocks
//    grouped per XCD for Wr L2 locality).
//  - s_setprio(1) around the MFMA cluster.
//
// ws layout (bytes):
//   Cc 0..25,165,824 | Wr ..27,377,664 | W2 ..27,869,184 | oI ..28,164,096
//   oWt ..28,753,920 | hoffG ..28,758,016 | Xp ..39,909,376 | Sd ..134,281,216

typedef __attribute__((ext_vector_type(4))) float f32x4;
typedef __attribute__((ext_vector_type(8))) short bf16x8;

typedef __attribute__((address_space(1))) const unsigned int uint_as1;
typedef __attribute__((address_space(3))) unsigned int uint_as3;

__device__ __forceinline__ void gl_lds16(const void* g, void* l) {
    __builtin_amdgcn_global_load_lds((uint_as1*)g, (uint_as3*)l, 16, 0, 0);
}

__device__ __forceinline__ unsigned short f2b(float f) {
    union { float f; uint32_t u; } v; v.f = f;
    uint32_t r = (v.u + 0x7FFFu + ((v.u >> 16) & 1u)) >> 16;
    return (unsigned short)r;
}
__device__ __forceinline__ float b2f(unsigned short h) {
    union { uint32_t u; float f; } v; v.u = ((uint32_t)h) << 16;
    return v.f;
}
__device__ __forceinline__ float b2f_lo(uint32_t u) {
    union { uint32_t u; float f; } v; v.u = u << 16;
    return v.f;
}
__device__ __forceinline__ float b2f_hi(uint32_t u) {
    union { uint32_t u; float f; } v; v.u = u & 0xFFFF0000u;
    return v.f;
}
__device__ __forceinline__ uint32_t pack2(float lo, float hi) {
    return (uint32_t)f2b(lo) | ((uint32_t)f2b(hi) << 16);
}

// ---------------------------------------------------------------------------
// Fused prep. [0,144) bilinear; [144,4464) Wr (K-major packed-8);
// [4464,5424) W2 (K-major packed-8); [5424,5426) hoffG; [5426,6107) zero Xp.
__global__ __launch_bounds__(256) void k_prep(const float* __restrict__ off,
                                              const float* __restrict__ w,
                                              const float* __restrict__ wd,
                                              const float* __restrict__ wu,
                                              uint32_t* __restrict__ oIdx,
                                              float* __restrict__ oW,
                                              unsigned short* __restrict__ Wr,
                                              unsigned short* __restrict__ W2,
                                              int* __restrict__ hoffG,
                                              unsigned short* __restrict__ Xp)
{
    const int bx = blockIdx.x, tid = threadIdx.x;
    if (bx < 144) {
        int gid = bx * 256 + tid;                    // 9*4096 exact
        int k = gid >> 12;
        int p = gid & 4095;
        int i = p >> 6, j = p & 63;
        float dy = off[(2 * k) * 4096 + p];
        float dx = off[(2 * k + 1) * 4096 + p];
        float py = (float)(i - 1 + k / 3) + dy;
        float px = (float)(j - 1 + k % 3) + dx;
        float fy = floorf(py), fx = floorf(px);
        float wy = py - fy, wx = px - fx;
        fy = fminf(fmaxf(fy, -100.f), 100.f);
        fx = fminf(fmaxf(fx, -100.f), 100.f);
        int y0 = (int)fy, x0 = (int)fx;
        float vy0 = (y0 >= 0 && y0 < 64) ? 1.f : 0.f;
        float vy1 = (y0 >= -1 && y0 < 63) ? 1.f : 0.f;
        float vx0 = (x0 >= 0 && x0 < 64) ? 1.f : 0.f;
        float vx1 = (x0 >= -1 && x0 < 63) ? 1.f : 0.f;
        float w00 = (1.f - wy) * (1.f - wx) * vy0 * vx0;
        float w01 = (1.f - wy) * wx * vy0 * vx1;
        float w10 = wy * (1.f - wx) * vy1 * vx0;
        float w11 = wy * wx * vy1 * vx1;
        int ya = min(max(y0, 0), 63), yb = min(max(y0 + 1, 0), 63);
        int xa = min(max(x0, 0), 63), xb = min(max(x0 + 1, 0), 63);
        oIdx[gid * 2 + 0] = (uint32_t)(ya * 64 + xa) | ((uint32_t)(ya * 64 + xb) << 16);
        oIdx[gid * 2 + 1] = (uint32_t)(yb * 64 + xa) | ((uint32_t)(yb * 64 + xb) << 16);
        oW[gid * 4 + 0] = w00;
        oW[gid * 4 + 1] = w01;
        oW[gid * 4 + 2] = w10;
        oW[gid * 4 + 3] = w11;
    } else if (bx < 4464) {
        int gid = (bx - 144) * 256 + tid;            // 384*2880 exact
        int o = gid / 2880, kk = gid % 2880;
        int g = kk / 72, r = kk % 72, k = r >> 3, cl = r & 7, c = g * 8 + cl;
        float v = (o < 320) ? w[((size_t)o * 320 + c) * 9 + k] : 0.f;
        Wr[(size_t)((kk >> 3) * 384 + o) * 8 + (kk & 7)] = f2b(v);
    } else if (bx < 5424) {
        int gid = (bx - 4464) * 256 + tid;           // 384*640 exact
        int o = gid / 640, kk2 = gid % 640;
        float acc = 0.f;
        if (o < 320) {
            for (int l = 0; l < 320; ++l)
                acc += wu[o * 320 + l] * wd[l * 640 + kk2];
        }
        W2[(size_t)((kk2 >> 3) * 384 + o) * 8 + (kk2 & 7)] = f2b(acc);
    } else if (bx < 5426) {
        int kkb = (bx - 5424) * 256 + tid;           // 360 entries
        if (kkb < 360) {
            int g = kkb / 9, k = kkb % 9;
            hoffG[kkb] = (g * 17424 + (k / 3) * 66 + (k % 3)) * 8; // ushort units
        }
    } else {
        // zero Xp: 696,960 int4 units
        int bz = bx - 5426;                          // 681 blocks
        #pragma unroll
        for (int j = 0; j < 4; ++j) {
            int u = bz * 1024 + j * 256 + tid;
            if (u < 696960) {
                int4 z = {0, 0, 0, 0};
                ((int4*)Xp)[u] = z;
            }
        }
    }
}

// ---------------------------------------------------------------------------
// Gather (rounds-7..9-verified): stage 8 bf16 x-planes once; emit bilinear
// im2col (9 stores/px) + padded pack-8 x copy (1 store/px).
__global__ __launch_bounds__(256) void k_gather(const float* __restrict__ x,
                                                const uint32_t* __restrict__ oIdx,
                                                const float* __restrict__ oW,
                                                unsigned short* __restrict__ Sd,
                                                unsigned short* __restrict__ Xp)
{
    __shared__ __align__(16) uint32_t pl32[4096 * 4];   // 64 KB
    const int tid = threadIdx.x;
    const int split = blockIdx.x, gl = blockIdx.y, b = blockIdx.z;
    const float* xb = x + ((size_t)b * 320 + gl * 8) * 4096;
    #pragma unroll 8
    for (int it = 0; it < 64; ++it) {
        int u = it * 256 + tid;
        int p = u & 3, px = u >> 2;
        float va = xb[(size_t)(2 * p) * 4096 + px];
        float vb = xb[(size_t)(2 * p + 1) * 4096 + px];
        pl32[px * 4 + p] = pack2(va, vb);
    }
    __syncthreads();

    for (int i = 0; i < 4; ++i) {
        int px = split * 1024 + i * 256 + tid;
        int nb = b * 4096 + px;
        int row = px >> 6, col = px & 63;
        {
            int4 st = *(const int4*)&pl32[px * 4];
            size_t a = ((size_t)(gl * 4 + b) * 4356 + (row + 1) * 66 + (col + 1)) * 8;
            *(int4*)(Xp + a) = st;
        }
        #pragma unroll
        for (int k = 0; k < 9; ++k) {
            int gi = k * 4096 + px;
            uint32_t i0 = oIdx[gi * 2], i1 = oIdx[gi * 2 + 1];
            float4 w = *(const float4*)&oW[gi * 4];
            int4 t0 = *(const int4*)&pl32[(i0 & 0xFFFFu) * 4];
            int4 t1 = *(const int4*)&pl32[(i0 >> 16) * 4];
            int4 t2 = *(const int4*)&pl32[(i1 & 0xFFFFu) * 4];
            int4 t3 = *(const int4*)&pl32[(i1 >> 16) * 4];
            float ac[8];
            #pragma unroll
            for (int q = 0; q < 8; ++q) ac[q] = 0.f;
#define TAP(tv, wv) \
    ac[0] += wv * b2f_lo((uint32_t)tv.x); ac[1] += wv * b2f_hi((uint32_t)tv.x); \
    ac[2] += wv * b2f_lo((uint32_t)tv.y); ac[3] += wv * b2f_hi((uint32_t)tv.y); \
    ac[4] += wv * b2f_lo((uint32_t)tv.z); ac[5] += wv * b2f_hi((uint32_t)tv.z); \
    ac[6] += wv * b2f_lo((uint32_t)tv.w); ac[7] += wv * b2f_hi((uint32_t)tv.w);
            TAP(t0, w.x) TAP(t1, w.y) TAP(t2, w.z) TAP(t3, w.w)
#undef TAP
            int4 st;
            st.x = (int)pack2(ac[0], ac[1]);
            st.y = (int)pack2(ac[2], ac[3]);
            st.z = (int)pack2(ac[4], ac[5]);
            st.w = (int)pack2(ac[6], ac[7]);
            *(int4*)(Sd + ((size_t)(gl * 9 + k) * 16384 + nb) * 8) = st;
        }
    }
}

// ---------------------------------------------------------------------------
// MFMA GEMM (round 4, see header comment): A global->VGPR, B dbuf LDS.
__global__ __launch_bounds__(256, 3) void k_gemm(const unsigned short* __restrict__ Sd,
                                                 const unsigned short* __restrict__ Xp,
                                                 const int* __restrict__ hoffG,
                                                 const unsigned short* __restrict__ Wr,
                                                 unsigned short* __restrict__ Cc,
                                                 const float* __restrict__ bias)
{
    __shared__ __align__(16) unsigned short Bs[2][8 * 128 * 8];   // 2 x 16 KB
    const int tid = threadIdx.x;
    // Bijective XCD swizzle: nwg=512, 512%8==0, 64 consecutive work-ids per
    // XCD; chunks never span m-halves (256/64=4 chunks per by) -> each XCD
    // sees one Wr m-panel at a time (L2 locality).
    const int flat = blockIdx.y * 256 + blockIdx.x;
    const int swz = (flat & 7) * 64 + (flat >> 3);
    const int n0 = (swz & 255) * 128, m0 = (swz >> 8) * 160;
    const int lane = tid & 63, w = tid >> 6;
    const int wm = w & 1, wn = w >> 1;
    const int quad = lane >> 4, nl = lane & 15;
    const bool hHalf = (n0 >= 16384);
    int xbase;
    {
        int nn = (n0 - 16384) + (tid & 127);
        int b = nn >> 12, px = nn & 4095;
        xbase = (b * 4356 + (px >> 6) * 66 + (px & 63)) * 8;
    }
    // A-fragment base: elem(s,kc,mt) at Abase + ((s*8+kc*4)*384 + mt*16)*8.
    const unsigned short* Abase = Wr + ((size_t)quad * 384 + m0 + wm * 80 + nl) * 8;

#define STAGE_B(buf, s1) do { \
    if (!hHalf) { \
        _Pragma("unroll") \
        for (int q_ = 0; q_ < 4; ++q_) { \
            int u_ = tid + q_ * 256; \
            int row_ = u_ >> 7, nn_ = n0 + (u_ & 127); \
            gl_lds16(Sd + ((size_t)((s1) * 8 + row_) * 16384 + nn_) * 8, &Bs[buf][u_ * 8]); \
        } \
    } else { \
        _Pragma("unroll") \
        for (int q_ = 0; q_ < 4; ++q_) { \
            int u_ = tid + q_ * 256; \
            int kkb_ = (s1) * 8 + (u_ >> 7); \
            int off_ = hoffG[__builtin_amdgcn_readfirstlane(kkb_)]; \
            gl_lds16(Xp + (size_t)(xbase + off_), &Bs[buf][u_ * 8]); \
        } \
    } \
} while (0)

    f32x4 acc[5][4];
    #pragma unroll
    for (int mt = 0; mt < 5; ++mt)
        #pragma unroll
        for (int nt = 0; nt < 4; ++nt)
            acc[mt][nt] = 0.f;

    // Prologue: stage tile 0 into buf 0, drain once (startup only).
    STAGE_B(0, 0);
    asm volatile("s_waitcnt vmcnt(0)" ::: "memory");
    __builtin_amdgcn_s_barrier();
    __builtin_amdgcn_sched_barrier(0);

    for (int s = 0; s < 45; ++s) {
        const int p = s & 1, np = p ^ 1;
        // Issue next tile's B staging first; HBM/L3 latency hides under the
        // A-loads + 40 MFMAs below.
        if (s < 44) STAGE_B(np, s + 1);
        __builtin_amdgcn_sched_barrier(0);
        #pragma unroll
        for (int kc = 0; kc < 2; ++kc) {
            bf16x8 a[5], bf[4];
            #pragma unroll
            for (int mt = 0; mt < 5; ++mt)
                a[mt] = *(const bf16x8*)(Abase + ((size_t)((s * 8 + kc * 4) * 384) + mt * 16) * 8);
            #pragma unroll
            for (int nt = 0; nt < 4; ++nt)
                bf[nt] = *(const bf16x8*)&Bs[p][((kc * 4 + quad) * 128 + wn * 64 + nt * 16 + nl) * 8];
            __builtin_amdgcn_s_setprio(1);
            #pragma unroll
            for (int mt = 0; mt < 5; ++mt)
                #pragma unroll
                for (int nt = 0; nt < 4; ++nt)
                    acc[mt][nt] = __builtin_amdgcn_mfma_f32_16x16x32_bf16(a[mt], bf[nt], acc[mt][nt], 0, 0, 0);
            __builtin_amdgcn_s_setprio(0);
        }
        // B staging for buf[np] must have landed before any wave crosses.
        asm volatile("s_waitcnt vmcnt(0)" ::: "memory");
        __builtin_amdgcn_s_barrier();
        __builtin_amdgcn_sched_barrier(0);
    }

    // Epilogue: bias + pack to Cc. o0 = m0 + wm*80 + mt*16 + quad*4 < 320.
    #pragma unroll
    for (int mt = 0; mt < 5; ++mt) {
        int o0 = m0 + wm * 80 + mt * 16 + quad * 4;
        float bv0 = bias[o0 + 0];
        float bv1 = bias[o0 + 1];
        float bv2 = bias[o0 + 2];
        float bv3 = bias[o0 + 3];
        #pragma unroll
        for (int nt = 0; nt < 4; ++nt) {
            int n2 = n0 + wn * 64 + nt * 16 + nl;
            unsigned short* pp = Cc + ((size_t)(o0 >> 3) * 32768 + n2) * 8 + (o0 & 7);
            ushort4 st;
            st.x = f2b(acc[mt][nt][0] + bv0);
            st.y = f2b(acc[mt][nt][1] + bv1);
            st.z = f2b(acc[mt][nt][2] + bv2);
            st.w = f2b(acc[mt][nt][3] + bv3);
            *(ushort4*)pp = st;
        }
    }
#undef STAGE_B
}

// ---------------------------------------------------------------------------
// Final: out = h + scale * (W2 x [dconv; h]), K=640 as 10 BK=64 steps.
// W2 K-major packed-8 -> coalesced stage -> conflict-free [kq][m] LDS.
__global__ __launch_bounds__(256) void k_final(const unsigned short* __restrict__ W2,
                                               const unsigned short* __restrict__ Cc,
                                               const float* __restrict__ scale,
                                               float* __restrict__ out)
{
    __shared__ __align__(16) unsigned short As[128 * 64];
    __shared__ __align__(16) unsigned short Bs[64 * 128];
    const int tid = threadIdx.x;
    const int n0 = blockIdx.x * 128, m0 = blockIdx.y * 128;
    const int lane = tid & 63, w = tid >> 6;
    const int wm = w & 1, wn = w >> 1;
    const int quad = lane >> 4, nl = lane & 15;
    const bool mActive = (m0 + wm * 64) < 320;
    f32x4 acc[4][4];
    #pragma unroll
    for (int mt = 0; mt < 4; ++mt)
        #pragma unroll
        for (int nt = 0; nt < 4; ++nt)
            acc[mt][nt] = 0.f;

    for (int s = 0; s < 10; ++s) {
        __syncthreads();
        #pragma unroll
        for (int q = 0; q < 4; ++q) {
            int u = tid + q * 256;
            int kq = u >> 7, m = u & 127;
            gl_lds16(W2 + ((size_t)(s * 8 + kq) * 384 + m0 + m) * 8, &As[u * 8]);
        }
        int h_off = (s < 5) ? 0 : 16384;
        int gq = (s < 5) ? s * 8 : (s - 5) * 8;
        #pragma unroll
        for (int q = 0; q < 4; ++q) {
            int u = tid + q * 256;
            int row = u >> 7, nn = n0 + (u & 127);
            gl_lds16(Cc + ((size_t)(gq + row) * 32768 + h_off + nn) * 8, &Bs[u * 8]);
        }
        __syncthreads();
        if (mActive) {
            #pragma unroll
            for (int kc = 0; kc < 2; ++kc) {
                bf16x8 a[4], bf[4];
                #pragma unroll
                for (int mt = 0; mt < 4; ++mt)
                    a[mt] = *(const bf16x8*)&As[((kc * 4 + quad) * 128 + wm * 64 + mt * 16 + nl) * 8];
                #pragma unroll
                for (int nt = 0; nt < 4; ++nt)
                    bf[nt] = *(const bf16x8*)&Bs[((kc * 4 + quad) * 128 + wn * 64 + nt * 16 + nl) * 8];
                #pragma unroll
                for (int mt = 0; mt < 4; ++mt)
                    #pragma unroll
                    for (int nt = 0; nt < 4; ++nt)
                        acc[mt][nt] = __builtin_amdgcn_mfma_f32_16x16x32_bf16(a[mt], bf[nt], acc[mt][nt], 0, 0, 0);
            }
        }
    }

    float sc = scale[0];
    if (mActive) {
        #pragma unroll
        for (int mt = 0; mt < 4; ++mt) {
            int o0 = m0 + wm * 64 + mt * 16 + quad * 4;
            if (o0 >= 320) continue;
            #pragma unroll
            for (int nt = 0; nt < 4; ++nt) {
                int n = n0 + wn * 64 + nt * 16 + nl;
                int b = n >> 12, px = n & 4095;
                ushort4 hv = *(const ushort4*)(Cc + ((size_t)(o0 >> 3) * 32768 + n + 16384) * 8 + (o0 & 7));
                size_t base = ((size_t)(b * 320 + o0)) * 4096 + px;
                out[base]            = b2f(hv.x) + sc * acc[mt][nt][0];
                out[base + 4096]     = b2f(hv.y) + sc * acc[mt][nt][1];
                out[base + 2 * 4096] = b2f(hv.z) + sc * acc[mt][nt][2];
                out[base + 3 * 4096] = b2f(hv.w) + sc * acc[mt][nt][3];
            }
        }
    }
}

// ---------------------------------------------------------------------------
extern "C" void kernel_launch(void* const* d_in, const int* in_sizes, int n_in,
                              void* d_out, int out_size, void* d_ws, size_t ws_size,
                              hipStream_t stream)
{
    const float* x      = (const float*)d_in[0];
    const float* weight = (const float*)d_in[1];
    const float* bias   = (const float*)d_in[2];
    const float* w_down = (const float*)d_in[3];
    const float* w_up   = (const float*)d_in[4];
    const float* scale  = (const float*)d_in[5];
    const float* offset = (const float*)d_in[6];
    char* ws = (char*)d_ws;
    unsigned short* Cc    = (unsigned short*)(ws + 0);
    unsigned short* Wr    = (unsigned short*)(ws + 25165824);
    unsigned short* W2    = (unsigned short*)(ws + 27377664);
    uint32_t*       oI    = (uint32_t*)(ws + 27869184);
    float*          oWt   = (float*)(ws + 28164096);
    int*            hoffG = (int*)(ws + 28753920);
    unsigned short* Xp    = (unsigned short*)(ws + 28758016);
    unsigned short* Sd    = (unsigned short*)(ws + 39909376);
    float* out = (float*)d_out;

    hipLaunchKernelGGL(k_prep, dim3(6107), dim3(256), 0, stream,
                       offset, weight, w_down, w_up, oI, oWt, Wr, W2, hoffG, Xp);
    hipLaunchKernelGGL(k_gather, dim3(4, 40, 4), dim3(256), 0, stream,
                       x, oI, oWt, Sd, Xp);
    hipLaunchKernelGGL(k_gemm, dim3(256, 2), dim3(256), 0, stream,
                       Sd, Xp, hoffG, Wr, Cc, bias);
    hipLaunchKernelGGL(k_final, dim3(128, 3), dim3(256), 0, stream,
                       W2, Cc, scale, out);
}

// Round 5
// 233.688 us; speedup vs baseline: 1.0621x; 1.0621x over previous
//
#include <hip/hip_runtime.h>
#include <stdint.h>

// B=4, C=O=320, H=W=64 -> HW=4096, N2=32768 (dconv n<16384, h n>=16384),
// K=2880 (M pad 384 in Wr only), Kf=640.
// K-permutation: kk = g*72 + k*8 + cl, c = g*8+cl (g<40, k<9, cl<8); kkb=kk>>3=g*9+k.
// Sd packed-8 (dconv only): elem(kk,n) at ushort idx (kkb*16384+n)*8 + (kk&7).
// Xp (padded x, h half): [g][b][py 66][px 66][cl 8] bf16; interior = x, halo = 0.
// Cc packed-8: elem(o,n2) at (o>>3)*32768*8 + n2*8 + (o&7).
// Wr K-major packed-8: elem(o,kk) at (kkb*384 + o)*8 + (kk&7). W2 likewise (Kf).
//
// Round 5: k_gemm reverted to the round-2 best (67.0 us, ~901 TF = m97-
// structure ceiling; 4 schedule variants all regressed -> TLP-saturated).
// This round attacks the non-GEMM time:
//  - k_pack (new): x -> Xp interior once (bf16 pack). k_gather stages its
//    LDS from Xp (int4 copies, L3-hot) instead of re-reading/re-packing x
//    4x (saves ~63 MB HBM + 3/4 of pack VALU), and drops its Xp store.
//  - k_final: BM=160 geometry (grid 128x2, per-wave 80x64, zero M-pad);
//    was BM=128 grid 128x3 with 1/3 idle waves.
//  - k_prep Wr repack: one thread per (kkb,o) -> ushort8 coalesced 16B
//    store (was 8 scattered 2B stores).
//
// ws layout (bytes):
//   Cc 0..25,165,824 | Wr ..27,377,664 | W2 ..27,869,184 | oI ..28,164,096
//   oWt ..28,753,920 | hoffG ..28,758,016 | Xp ..39,909,376 | Sd ..134,281,216

typedef __attribute__((ext_vector_type(4))) float f32x4;
typedef __attribute__((ext_vector_type(8))) short bf16x8;

typedef __attribute__((address_space(1))) const unsigned int uint_as1;
typedef __attribute__((address_space(3))) unsigned int uint_as3;

__device__ __forceinline__ void gl_lds16(const void* g, void* l) {
    __builtin_amdgcn_global_load_lds((uint_as1*)g, (uint_as3*)l, 16, 0, 0);
}

__device__ __forceinline__ unsigned short f2b(float f) {
    union { float f; uint32_t u; } v; v.f = f;
    uint32_t r = (v.u + 0x7FFFu + ((v.u >> 16) & 1u)) >> 16;
    return (unsigned short)r;
}
__device__ __forceinline__ float b2f(unsigned short h) {
    union { uint32_t u; float f; } v; v.u = ((uint32_t)h) << 16;
    return v.f;
}
__device__ __forceinline__ float b2f_lo(uint32_t u) {
    union { uint32_t u; float f; } v; v.u = u << 16;
    return v.f;
}
__device__ __forceinline__ float b2f_hi(uint32_t u) {
    union { uint32_t u; float f; } v; v.u = u & 0xFFFF0000u;
    return v.f;
}
__device__ __forceinline__ uint32_t pack2(float lo, float hi) {
    return (uint32_t)f2b(lo) | ((uint32_t)f2b(hi) << 16);
}

// ---------------------------------------------------------------------------
// Fused prep. [0,144) bilinear; [144,684) Wr (ushort8 coalesced);
// [684,1644) W2; [1644,1646) hoffG; [1646,2327) zero Xp (halo+interior;
// interior is overwritten later by k_pack).
__global__ __launch_bounds__(256) void k_prep(const float* __restrict__ off,
                                              const float* __restrict__ w,
                                              const float* __restrict__ wd,
                                              const float* __restrict__ wu,
                                              uint32_t* __restrict__ oIdx,
                                              float* __restrict__ oW,
                                              unsigned short* __restrict__ Wr,
                                              unsigned short* __restrict__ W2,
                                              int* __restrict__ hoffG,
                                              unsigned short* __restrict__ Xp)
{
    const int bx = blockIdx.x, tid = threadIdx.x;
    if (bx < 144) {
        int gid = bx * 256 + tid;                    // 9*4096 exact
        int k = gid >> 12;
        int p = gid & 4095;
        int i = p >> 6, j = p & 63;
        float dy = off[(2 * k) * 4096 + p];
        float dx = off[(2 * k + 1) * 4096 + p];
        float py = (float)(i - 1 + k / 3) + dy;
        float px = (float)(j - 1 + k % 3) + dx;
        float fy = floorf(py), fx = floorf(px);
        float wy = py - fy, wx = px - fx;
        fy = fminf(fmaxf(fy, -100.f), 100.f);
        fx = fminf(fmaxf(fx, -100.f), 100.f);
        int y0 = (int)fy, x0 = (int)fx;
        float vy0 = (y0 >= 0 && y0 < 64) ? 1.f : 0.f;
        float vy1 = (y0 >= -1 && y0 < 63) ? 1.f : 0.f;
        float vx0 = (x0 >= 0 && x0 < 64) ? 1.f : 0.f;
        float vx1 = (x0 >= -1 && x0 < 63) ? 1.f : 0.f;
        float w00 = (1.f - wy) * (1.f - wx) * vy0 * vx0;
        float w01 = (1.f - wy) * wx * vy0 * vx1;
        float w10 = wy * (1.f - wx) * vy1 * vx0;
        float w11 = wy * wx * vy1 * vx1;
        int ya = min(max(y0, 0), 63), yb = min(max(y0 + 1, 0), 63);
        int xa = min(max(x0, 0), 63), xb = min(max(x0 + 1, 0), 63);
        oIdx[gid * 2 + 0] = (uint32_t)(ya * 64 + xa) | ((uint32_t)(ya * 64 + xb) << 16);
        oIdx[gid * 2 + 1] = (uint32_t)(yb * 64 + xa) | ((uint32_t)(yb * 64 + xb) << 16);
        oW[gid * 4 + 0] = w00;
        oW[gid * 4 + 1] = w01;
        oW[gid * 4 + 2] = w10;
        oW[gid * 4 + 3] = w11;
    } else if (bx < 684) {
        // Wr: one thread per (kkb,o), ushort8 coalesced store. 540*256 =
        // 138240 = 360*384 exact.
        int gid = (bx - 144) * 256 + tid;
        int kkb = gid / 384, o = gid - kkb * 384;    // consecutive tid -> o
        int g = kkb / 9, k = kkb - g * 9;
        float v[8];
        #pragma unroll
        for (int cl = 0; cl < 8; ++cl) {
            int c = g * 8 + cl;
            v[cl] = (o < 320) ? w[((size_t)o * 320 + c) * 9 + k] : 0.f;
        }
        int4 st;
        st.x = (int)pack2(v[0], v[1]);
        st.y = (int)pack2(v[2], v[3]);
        st.z = (int)pack2(v[4], v[5]);
        st.w = (int)pack2(v[6], v[7]);
        *(int4*)(Wr + (size_t)gid * 8) = st;
    } else if (bx < 1644) {
        int gid = (bx - 684) * 256 + tid;            // 384*640 exact
        int o = gid / 640, kk2 = gid % 640;
        float acc = 0.f;
        if (o < 320) {
            for (int l = 0; l < 320; ++l)
                acc += wu[o * 320 + l] * wd[l * 640 + kk2];
        }
        W2[(size_t)((kk2 >> 3) * 384 + o) * 8 + (kk2 & 7)] = f2b(acc);
    } else if (bx < 1646) {
        int kkb = (bx - 1644) * 256 + tid;           // 360 entries
        if (kkb < 360) {
            int g = kkb / 9, k = kkb % 9;
            hoffG[kkb] = (g * 17424 + (k / 3) * 66 + (k % 3)) * 8; // ushort units
        }
    } else {
        // zero Xp: 696,960 int4 units
        int bz = bx - 1646;                          // 681 blocks
        #pragma unroll
        for (int j = 0; j < 4; ++j) {
            int u = bz * 1024 + j * 256 + tid;
            if (u < 696960) {
                int4 z = {0, 0, 0, 0};
                ((int4*)Xp)[u] = z;
            }
        }
    }
}

// ---------------------------------------------------------------------------
// Pack x -> Xp interior (bf16 packed-8, 66x66 padded planes). Halo was
// zeroed by k_prep; interior/halo are disjoint so no ordering hazard.
__global__ __launch_bounds__(256) void k_pack(const float* __restrict__ x,
                                              unsigned short* __restrict__ Xp)
{
    const int tid = threadIdx.x;
    const int sp = blockIdx.x, gl = blockIdx.y, b = blockIdx.z;
    const float* xb = x + ((size_t)b * 320 + gl * 8) * 4096;
    unsigned short* xpb = Xp + (size_t)(gl * 4 + b) * 4356 * 8;
    #pragma unroll
    for (int i = 0; i < 4; ++i) {
        int px = sp * 1024 + i * 256 + tid;
        float v0 = xb[0 * 4096 + px], v1 = xb[1 * 4096 + px];
        float v2 = xb[2 * 4096 + px], v3 = xb[3 * 4096 + px];
        float v4 = xb[4 * 4096 + px], v5 = xb[5 * 4096 + px];
        float v6 = xb[6 * 4096 + px], v7 = xb[7 * 4096 + px];
        int4 st;
        st.x = (int)pack2(v0, v1);
        st.y = (int)pack2(v2, v3);
        st.z = (int)pack2(v4, v5);
        st.w = (int)pack2(v6, v7);
        *(int4*)(xpb + (((px >> 6) + 1) * 66 + (px & 63) + 1) * 8) = st;
    }
}

// ---------------------------------------------------------------------------
// Gather: stage 8 bf16 x-planes from Xp (int4 copies, L3-hot, no repack);
// emit bilinear im2col (9 stores/px).
__global__ __launch_bounds__(256) void k_gather(const uint32_t* __restrict__ oIdx,
                                                const float* __restrict__ oW,
                                                const unsigned short* __restrict__ Xp,
                                                unsigned short* __restrict__ Sd)
{
    __shared__ __align__(16) uint32_t pl32[4096 * 4];   // 64 KB
    const int tid = threadIdx.x;
    const int split = blockIdx.x, gl = blockIdx.y, b = blockIdx.z;
    const unsigned short* xpb = Xp + (size_t)(gl * 4 + b) * 4356 * 8;
    #pragma unroll 4
    for (int it = 0; it < 16; ++it) {
        int px = it * 256 + tid;
        int4 v = *(const int4*)(xpb + (((px >> 6) + 1) * 66 + (px & 63) + 1) * 8);
        *(int4*)&pl32[px * 4] = v;
    }
    __syncthreads();

    for (int i = 0; i < 4; ++i) {
        int px = split * 1024 + i * 256 + tid;
        int nb = b * 4096 + px;
        #pragma unroll
        for (int k = 0; k < 9; ++k) {
            int gi = k * 4096 + px;
            uint32_t i0 = oIdx[gi * 2], i1 = oIdx[gi * 2 + 1];
            float4 w = *(const float4*)&oW[gi * 4];
            int4 t0 = *(const int4*)&pl32[(i0 & 0xFFFFu) * 4];
            int4 t1 = *(const int4*)&pl32[(i0 >> 16) * 4];
            int4 t2 = *(const int4*)&pl32[(i1 & 0xFFFFu) * 4];
            int4 t3 = *(const int4*)&pl32[(i1 >> 16) * 4];
            float ac[8];
            #pragma unroll
            for (int q = 0; q < 8; ++q) ac[q] = 0.f;
#define TAP(tv, wv) \
    ac[0] += wv * b2f_lo((uint32_t)tv.x); ac[1] += wv * b2f_hi((uint32_t)tv.x); \
    ac[2] += wv * b2f_lo((uint32_t)tv.y); ac[3] += wv * b2f_hi((uint32_t)tv.y); \
    ac[4] += wv * b2f_lo((uint32_t)tv.z); ac[5] += wv * b2f_hi((uint32_t)tv.z); \
    ac[6] += wv * b2f_lo((uint32_t)tv.w); ac[7] += wv * b2f_hi((uint32_t)tv.w);
            TAP(t0, w.x) TAP(t1, w.y) TAP(t2, w.z) TAP(t3, w.w)
#undef TAP
            int4 st;
            st.x = (int)pack2(ac[0], ac[1]);
            st.y = (int)pack2(ac[2], ac[3]);
            st.z = (int)pack2(ac[4], ac[5]);
            st.w = (int)pack2(ac[6], ac[7]);
            *(int4*)(Sd + ((size_t)(gl * 9 + k) * 16384 + nb) * 8) = st;
        }
    }
}

// ---------------------------------------------------------------------------
// MFMA GEMM (round-2 best, verbatim): BM=160, BN=128, BK=64, 4 waves 2Mx2N,
// per-wave 80x64, acc 5x4. Double-buffered LDS (72 KB -> 2 blocks/CU),
// grid 256x2 = 512 = exactly 2/CU, zero M-padding. Minimum-2-phase schedule.
__global__ __launch_bounds__(256) void k_gemm(const unsigned short* __restrict__ Sd,
                                              const unsigned short* __restrict__ Xp,
                                              const int* __restrict__ hoffG,
                                              const unsigned short* __restrict__ Wr,
                                              unsigned short* __restrict__ Cc,
                                              const float* __restrict__ bias)
{
    __shared__ __align__(16) unsigned short As[2][8 * 160 * 8];   // 2 x 20 KB
    __shared__ __align__(16) unsigned short Bs[2][8 * 128 * 8];   // 2 x 16 KB
    const int tid = threadIdx.x;
    const int n0 = blockIdx.x * 128, m0 = blockIdx.y * 160;
    const int lane = tid & 63, w = tid >> 6;
    const int wm = w & 1, wn = w >> 1;
    const int quad = lane >> 4, nl = lane & 15;
    const bool hHalf = (n0 >= 16384);
    int xbase;
    {
        int nn = (n0 - 16384) + (tid & 127);
        int b = nn >> 12, px = nn & 4095;
        xbase = (b * 4356 + (px >> 6) * 66 + (px & 63)) * 8;
    }

#define STAGE(buf, s1) do { \
    _Pragma("unroll") \
    for (int q_ = 0; q_ < 5; ++q_) { \
        int u_ = tid + q_ * 256; \
        int kq_ = u_ / 160, m_ = u_ - kq_ * 160; \
        gl_lds16(Wr + ((size_t)(((s1) * 8 + kq_) * 384 + m0 + m_)) * 8, &As[buf][u_ * 8]); \
    } \
    if (!hHalf) { \
        _Pragma("unroll") \
        for (int q_ = 0; q_ < 4; ++q_) { \
            int u_ = tid + q_ * 256; \
            int row_ = u_ >> 7, nn_ = n0 + (u_ & 127); \
            gl_lds16(Sd + ((size_t)((s1) * 8 + row_) * 16384 + nn_) * 8, &Bs[buf][u_ * 8]); \
        } \
    } else { \
        _Pragma("unroll") \
        for (int q_ = 0; q_ < 4; ++q_) { \
            int u_ = tid + q_ * 256; \
            int kkb_ = (s1) * 8 + (u_ >> 7); \
            int off_ = hoffG[__builtin_amdgcn_readfirstlane(kkb_)]; \
            gl_lds16(Xp + (size_t)(xbase + off_), &Bs[buf][u_ * 8]); \
        } \
    } \
} while (0)

    f32x4 acc[5][4];
    #pragma unroll
    for (int mt = 0; mt < 5; ++mt)
        #pragma unroll
        for (int nt = 0; nt < 4; ++nt)
            acc[mt][nt] = 0.f;

    // Prologue: stage tile 0 into buf 0, drain once (startup only).
    STAGE(0, 0);
    asm volatile("s_waitcnt vmcnt(0)" ::: "memory");
    __builtin_amdgcn_s_barrier();
    __builtin_amdgcn_sched_barrier(0);

    for (int s = 0; s < 45; ++s) {
        const int p = s & 1, np = p ^ 1;
        // Issue next tile's staging FIRST; its HBM latency hides under the
        // 40 MFMAs below.
        if (s < 44) STAGE(np, s + 1);
        __builtin_amdgcn_sched_barrier(0);
        #pragma unroll
        for (int kc = 0; kc < 2; ++kc) {
            bf16x8 a[5], bf[4];
            #pragma unroll
            for (int mt = 0; mt < 5; ++mt)
                a[mt] = *(const bf16x8*)&As[p][((kc * 4 + quad) * 160 + wm * 80 + mt * 16 + nl) * 8];
            #pragma unroll
            for (int nt = 0; nt < 4; ++nt)
                bf[nt] = *(const bf16x8*)&Bs[p][((kc * 4 + quad) * 128 + wn * 64 + nt * 16 + nl) * 8];
            #pragma unroll
            for (int mt = 0; mt < 5; ++mt)
                #pragma unroll
                for (int nt = 0; nt < 4; ++nt)
                    acc[mt][nt] = __builtin_amdgcn_mfma_f32_16x16x32_bf16(a[mt], bf[nt], acc[mt][nt], 0, 0, 0);
        }
        asm volatile("s_waitcnt vmcnt(0)" ::: "memory");
        __builtin_amdgcn_s_barrier();
        __builtin_amdgcn_sched_barrier(0);
    }

    // Epilogue: bias + pack to Cc. o0 = m0 + wm*80 + mt*16 + quad*4 < 320.
    #pragma unroll
    for (int mt = 0; mt < 5; ++mt) {
        int o0 = m0 + wm * 80 + mt * 16 + quad * 4;
        float bv0 = bias[o0 + 0];
        float bv1 = bias[o0 + 1];
        float bv2 = bias[o0 + 2];
        float bv3 = bias[o0 + 3];
        #pragma unroll
        for (int nt = 0; nt < 4; ++nt) {
            int n2 = n0 + wn * 64 + nt * 16 + nl;
            unsigned short* pp = Cc + ((size_t)(o0 >> 3) * 32768 + n2) * 8 + (o0 & 7);
            ushort4 st;
            st.x = f2b(acc[mt][nt][0] + bv0);
            st.y = f2b(acc[mt][nt][1] + bv1);
            st.z = f2b(acc[mt][nt][2] + bv2);
            st.w = f2b(acc[mt][nt][3] + bv3);
            *(ushort4*)pp = st;
        }
    }
#undef STAGE
}

// ---------------------------------------------------------------------------
// Final: out = h + scale * (W2 x [dconv; h]), K=640 as 10 BK=64 steps.
// BM=160 geometry (grid 128x2, per-wave 80x64) -> zero M-pad, no idle waves.
__global__ __launch_bounds__(256) void k_final(const unsigned short* __restrict__ W2,
                                               const unsigned short* __restrict__ Cc,
                                               const float* __restrict__ scale,
                                               float* __restrict__ out)
{
    __shared__ __align__(16) unsigned short As[8 * 160 * 8];   // 20 KB
    __shared__ __align__(16) unsigned short Bs[8 * 128 * 8];   // 16 KB
    const int tid = threadIdx.x;
    const int n0 = blockIdx.x * 128, m0 = blockIdx.y * 160;
    const int lane = tid & 63, w = tid >> 6;
    const int wm = w & 1, wn = w >> 1;
    const int quad = lane >> 4, nl = lane & 15;
    f32x4 acc[5][4];
    #pragma unroll
    for (int mt = 0; mt < 5; ++mt)
        #pragma unroll
        for (int nt = 0; nt < 4; ++nt)
            acc[mt][nt] = 0.f;

    for (int s = 0; s < 10; ++s) {
        __syncthreads();
        #pragma unroll
        for (int q = 0; q < 5; ++q) {
            int u = tid + q * 256;
            int kq = u / 160, m = u - kq * 160;
            gl_lds16(W2 + ((size_t)(s * 8 + kq) * 384 + m0 + m) * 8, &As[u * 8]);
        }
        int h_off = (s < 5) ? 0 : 16384;
        int gq = (s < 5) ? s * 8 : (s - 5) * 8;
        #pragma unroll
        for (int q = 0; q < 4; ++q) {
            int u = tid + q * 256;
            int row = u >> 7, nn = n0 + (u & 127);
            gl_lds16(Cc + ((size_t)(gq + row) * 32768 + h_off + nn) * 8, &Bs[u * 8]);
        }
        __syncthreads();
        #pragma unroll
        for (int kc = 0; kc < 2; ++kc) {
            bf16x8 a[5], bf[4];
            #pragma unroll
            for (int mt = 0; mt < 5; ++mt)
                a[mt] = *(const bf16x8*)&As[((kc * 4 + quad) * 160 + wm * 80 + mt * 16 + nl) * 8];
            #pragma unroll
            for (int nt = 0; nt < 4; ++nt)
                bf[nt] = *(const bf16x8*)&Bs[((kc * 4 + quad) * 128 + wn * 64 + nt * 16 + nl) * 8];
            #pragma unroll
            for (int mt = 0; mt < 5; ++mt)
                #pragma unroll
                for (int nt = 0; nt < 4; ++nt)
                    acc[mt][nt] = __builtin_amdgcn_mfma_f32_16x16x32_bf16(a[mt], bf[nt], acc[mt][nt], 0, 0, 0);
        }
    }

    float sc = scale[0];
    #pragma unroll
    for (int mt = 0; mt < 5; ++mt) {
        int o0 = m0 + wm * 80 + mt * 16 + quad * 4;
        #pragma unroll
        for (int nt = 0; nt < 4; ++nt) {
            int n = n0 + wn * 64 + nt * 16 + nl;
            int b = n >> 12, px = n & 4095;
            ushort4 hv = *(const ushort4*)(Cc + ((size_t)(o0 >> 3) * 32768 + n + 16384) * 8 + (o0 & 7));
            size_t base = ((size_t)(b * 320 + o0)) * 4096 + px;
            out[base]            = b2f(hv.x) + sc * acc[mt][nt][0];
            out[base + 4096]     = b2f(hv.y) + sc * acc[mt][nt][1];
            out[base + 2 * 4096] = b2f(hv.z) + sc * acc[mt][nt][2];
            out[base + 3 * 4096] = b2f(hv.w) + sc * acc[mt][nt][3];
        }
    }
}

// ---------------------------------------------------------------------------
extern "C" void kernel_launch(void* const* d_in, const int* in_sizes, int n_in,
                              void* d_out, int out_size, void* d_ws, size_t ws_size,
                              hipStream_t stream)
{
    const float* x      = (const float*)d_in[0];
    const float* weight = (const float*)d_in[1];
    const float* bias   = (const float*)d_in[2];
    const float* w_down = (const float*)d_in[3];
    const float* w_up   = (const float*)d_in[4];
    const float* scale  = (const float*)d_in[5];
    const float* offset = (const float*)d_in[6];
    char* ws = (char*)d_ws;
    unsigned short* Cc    = (unsigned short*)(ws + 0);
    unsigned short* Wr    = (unsigned short*)(ws + 25165824);
    unsigned short* W2    = (unsigned short*)(ws + 27377664);
    uint32_t*       oI    = (uint32_t*)(ws + 27869184);
    float*          oWt   = (float*)(ws + 28164096);
    int*            hoffG = (int*)(ws + 28753920);
    unsigned short* Xp    = (unsigned short*)(ws + 28758016);
    unsigned short* Sd    = (unsigned short*)(ws + 39909376);
    float* out = (float*)d_out;

    hipLaunchKernelGGL(k_prep, dim3(2327), dim3(256), 0, stream,
                       offset, weight, w_down, w_up, oI, oWt, Wr, W2, hoffG, Xp);
    hipLaunchKernelGGL(k_pack, dim3(4, 40, 4), dim3(256), 0, stream,
                       x, Xp);
    hipLaunchKernelGGL(k_gather, dim3(4, 40, 4), dim3(256), 0, stream,
                       oI, oWt, Xp, Sd);
    hipLaunchKernelGGL(k_gemm, dim3(256, 2), dim3(256), 0, stream,
                       Sd, Xp, hoffG, Wr, Cc, bias);
    hipLaunchKernelGGL(k_final, dim3(128, 2), dim3(256), 0, stream,
                       W2, Cc, scale, out);
}